// Round 1
// baseline (257.413 us; speedup 1.0000x reference)
//
#include <hip/hip_runtime.h>

// CausalSelfAttention B=4, N=2048, D=1024, scale 1/32.
// f16 convert(+zero l) -> fused QKV GEMM -> S=QK^T 128x128 (fused mask+exp +
// atomic row sums) -> PV 128x128 (causal K-limit, heavy-first) / rowsum.
//
// R12: QKV GEMM rewritten as 256x256 / BK=64 / 8-wave 8-phase schedule
// (T2 swizzle + T3/T4 counted-vmcnt + T5 setprio). Evidence: R11 profile shows
// gemm_qkv = 69.9us at MfmaUtil 30%, HBM 23% -> structural barrier-drain stall
// of the 128^2 2-phase loop (~900 TF ceiling). 8-phase keeps 4 staging loads
// in flight across barriers (vmcnt(4) at phases 4/8 only, never 0 mid-loop).
// Region-liveness schedule: quadrants (mh,nh) 00,01,10,11; wave rows remapped
// mh*128+(w>>2)*64, cols nh*128+(w&3)*32 so each 128-row half of A/B dies at a
// known phase and is restaged exactly one phase later. Last iter peeled with
// vmcnt(0). S/PV staging unchanged from R11 (VGPR-prefetch 2-phase).

typedef __attribute__((ext_vector_type(8))) _Float16 half8;
typedef __attribute__((ext_vector_type(4))) _Float16 half4v;
typedef __attribute__((ext_vector_type(4))) float floatx4;

#define AS1 __attribute__((address_space(1)))
#define AS3 __attribute__((address_space(3)))

__device__ __forceinline__ void load16_lds(void* lds, const void* g) {
  __builtin_amdgcn_global_load_lds((AS1 void*)g, (AS3 void*)lds, 16, 0, 0);
}

// ---------------------------------------------------------------- conv + zero

__global__ __launch_bounds__(256)
void conv_f32_f16(const float* __restrict__ in, _Float16* __restrict__ out,
                  float* __restrict__ l) {
  if (blockIdx.x < 8192) {
    const int i = (blockIdx.x * 256 + threadIdx.x) << 2;
    float4 v = *(const float4*)(in + i);
    half4v o = { (_Float16)v.x, (_Float16)v.y, (_Float16)v.z, (_Float16)v.w };
    *(half4v*)(out + i) = o;
  } else {
    const int i = ((blockIdx.x - 8192) * 256 + threadIdx.x) << 2;
    *(float4*)(l + i) = float4{0.f, 0.f, 0.f, 0.f};
  }
}

// W [1024(k),1024(n)] fp32 -> Wt [n][k] f16 for 3 weights -> [3072][1024]
__global__ __launch_bounds__(256)
void transpose_w(const float* __restrict__ W0, const float* __restrict__ W1,
                 const float* __restrict__ W2, _Float16* __restrict__ Wt) {
  const float* W = blockIdx.z == 0 ? W0 : (blockIdx.z == 1 ? W1 : W2);
  _Float16* out = Wt + (long long)blockIdx.z * 1048576;
  __shared__ _Float16 t[32][33];
  const int tx = threadIdx.x, ty = threadIdx.y;
  const int n0 = blockIdx.x << 5, k0 = blockIdx.y << 5;
#pragma unroll
  for (int i = 0; i < 4; ++i)
    t[ty + i * 8][tx] = (_Float16)W[(long long)(k0 + ty + i * 8) * 1024 + n0 + tx];
  __syncthreads();
#pragma unroll
  for (int i = 0; i < 4; ++i)
    out[(long long)(n0 + ty + i * 8) * 1024 + k0 + tx] = t[tx][ty + i * 8];
}

// ---------------------------------------------------------------- QKV GEMM
// 256x256 tile, BK=64, 512 threads (8 waves: wm = w>>2 in {0,64}, wn = w&3).
// 8-phase schedule, double-buffered K-tiles, vmcnt(4) at phases 4/8.
__global__ __launch_bounds__(512)
void gemm_qkv(const _Float16* __restrict__ A, const _Float16* __restrict__ B,
              _Float16* __restrict__ Q, _Float16* __restrict__ Kh,
              _Float16* __restrict__ Vt) {
  // bijective XCD swizzle: 384 blocks, 48 per XCD, bm-major within XCD
  const int wg = ((blockIdx.x & 7) * 48) + (blockIdx.x >> 3);
  const int bm = wg / 12, bn = wg % 12;

  const _Float16* Ab = A + (long long)bm * 256 * 1024;
  const _Float16* Bb = B + (long long)bn * 256 * 1024;

  __shared__ _Float16 As[2][256][64];   // 64 KiB
  __shared__ _Float16 Bs[2][256][64];   // 64 KiB

  const int tid = threadIdx.x;
  const int wave = tid >> 6, lane = tid & 63;
  const int quad = lane >> 4, lr = lane & 15;
  const int wm64 = (wave >> 2) << 6;    // 0 / 64
  const int wn32 = (wave & 3) << 5;     // 0,32,64,96
  const int srow = lane >> 3;           // 0..7
  const int goff = ((lane & 7) ^ srow) << 3;  // pre-swizzled global chunk

  const _Float16* gA = Ab + (long long)(wave * 8 + srow) * 1024 + goff;
  const _Float16* gB = Bb + (long long)(wave * 8 + srow) * 1024 + goff;

  floatx4 acc[2][4][2][2] = {};
  half8 af[4][2], bf[2][2];

#define STAGE_A(buf, half, kt)                                                \
  load16_lds(&As[buf][(half) * 128 + wave * 8][0],                            \
             gA + ((half) * 128) * 1024 + (kt) * 64);                         \
  load16_lds(&As[buf][(half) * 128 + 64 + wave * 8][0],                       \
             gA + ((half) * 128 + 64) * 1024 + (kt) * 64)

#define STAGE_B(buf, half, kt)                                                \
  load16_lds(&Bs[buf][(half) * 128 + wave * 8][0],                            \
             gB + ((half) * 128) * 1024 + (kt) * 64);                         \
  load16_lds(&Bs[buf][(half) * 128 + 64 + wave * 8][0],                       \
             gB + ((half) * 128 + 64) * 1024 + (kt) * 64)

#define DSR(buf, mh, nh)                                                      \
  _Pragma("unroll") for (int ii = 0; ii < 4; ++ii) {                          \
    const int ra = (mh) * 128 + wm64 + (ii << 4) + lr;                        \
    af[ii][0] = *(const half8*)&As[buf][ra][((quad) ^ (ra & 7)) << 3];        \
    af[ii][1] = *(const half8*)&As[buf][ra][((4 + quad) ^ (ra & 7)) << 3];    \
  }                                                                           \
  _Pragma("unroll") for (int jj = 0; jj < 2; ++jj) {                          \
    const int rb = (nh) * 128 + wn32 + (jj << 4) + lr;                        \
    bf[jj][0] = *(const half8*)&Bs[buf][rb][((quad) ^ (rb & 7)) << 3];        \
    bf[jj][1] = *(const half8*)&Bs[buf][rb][((4 + quad) ^ (rb & 7)) << 3];    \
  }

#define MFMA8(mh, nh)                                                         \
  __builtin_amdgcn_s_setprio(1);                                              \
  _Pragma("unroll") for (int kk = 0; kk < 2; ++kk)                            \
  _Pragma("unroll") for (int ii = 0; ii < 4; ++ii)                            \
  _Pragma("unroll") for (int jj = 0; jj < 2; ++jj)                            \
    acc[mh][ii][nh][jj] = __builtin_amdgcn_mfma_f32_16x16x32_f16(             \
        af[ii][kk], bf[jj][kk], acc[mh][ii][nh][jj], 0, 0, 0);                \
  __builtin_amdgcn_s_setprio(0)

#define BAR() __builtin_amdgcn_s_barrier()
#define LGKM0()                                                               \
  do { asm volatile("s_waitcnt lgkmcnt(0)");                                  \
       __builtin_amdgcn_sched_barrier(0); } while (0)
#define VM4()                                                                 \
  do { asm volatile("s_waitcnt vmcnt(4)");                                    \
       __builtin_amdgcn_sched_barrier(0); } while (0)
#define VM0()                                                                 \
  do { asm volatile("s_waitcnt vmcnt(0)");                                    \
       __builtin_amdgcn_sched_barrier(0); } while (0)

  // prologue: tile0 -> buf0 (all 4 regions), tile1 lo halves -> buf1
  STAGE_A(0, 0, 0); STAGE_B(0, 0, 0); STAGE_A(0, 1, 0); STAGE_B(0, 1, 0);
  STAGE_A(1, 0, 1); STAGE_B(1, 0, 1);
  VM4();   // tile0's 8 loads landed; tile1's 4 may stay in flight
  BAR();

  // steady iterations: consume tiles 2i (buf0, ph1-4) and 2i+1 (buf1, ph5-8)
  for (int i = 0; i < 7; ++i) {
    const int t1 = 2 * i + 1, t2 = 2 * i + 2, t3 = 2 * i + 3;
    DSR(0, 0, 0); STAGE_A(1, 1, t1); BAR(); LGKM0(); MFMA8(0, 0); BAR();
    DSR(0, 0, 1); STAGE_B(1, 1, t1); BAR(); LGKM0(); MFMA8(0, 1); BAR();
    DSR(0, 1, 0); STAGE_A(0, 0, t2); BAR(); LGKM0(); MFMA8(1, 0); BAR();
    DSR(0, 1, 1); STAGE_B(0, 0, t2); BAR(); LGKM0(); MFMA8(1, 1); VM4(); BAR();
    DSR(1, 0, 0); STAGE_A(0, 1, t2); BAR(); LGKM0(); MFMA8(0, 0); BAR();
    DSR(1, 0, 1); STAGE_B(0, 1, t2); BAR(); LGKM0(); MFMA8(0, 1); BAR();
    DSR(1, 1, 0); STAGE_A(1, 0, t3); BAR(); LGKM0(); MFMA8(1, 0); BAR();
    DSR(1, 1, 1); STAGE_B(1, 0, t3); BAR(); LGKM0(); MFMA8(1, 1); VM4(); BAR();
  }

  // last iteration (tiles 14/15): finish tile15 hi halves, then drain
  DSR(0, 0, 0); STAGE_A(1, 1, 15); BAR(); LGKM0(); MFMA8(0, 0); BAR();
  DSR(0, 0, 1); STAGE_B(1, 1, 15); BAR(); LGKM0(); MFMA8(0, 1); BAR();
  DSR(0, 1, 0);                    BAR(); LGKM0(); MFMA8(1, 0); BAR();
  DSR(0, 1, 1);                    BAR(); LGKM0(); MFMA8(1, 1); VM0(); BAR();
  DSR(1, 0, 0);                    BAR(); LGKM0(); MFMA8(0, 0); BAR();
  DSR(1, 0, 1);                    BAR(); LGKM0(); MFMA8(0, 1); BAR();
  DSR(1, 1, 0);                    BAR(); LGKM0(); MFMA8(1, 0); BAR();
  DSR(1, 1, 1);                    BAR(); LGKM0(); MFMA8(1, 1);

#undef STAGE_A
#undef STAGE_B
#undef DSR
#undef MFMA8
#undef BAR
#undef LGKM0
#undef VM4
#undef VM0

  // epilogue: row = bm*256 + mh*128 + wm64 + ii*16 + quad*4 + r
  //           col = bn*256 + nh*128 + wn32 + jj*16 + lr
  const int rb0 = bm * 256 + wm64 + (quad << 2);
  const int cb0 = bn * 256 + wn32 + lr;

  if (bn < 8) {
    _Float16* C = (bn < 4) ? Q : Kh;
#pragma unroll
    for (int mh = 0; mh < 2; ++mh)
#pragma unroll
      for (int ii = 0; ii < 4; ++ii)
#pragma unroll
        for (int nh = 0; nh < 2; ++nh)
#pragma unroll
          for (int jj = 0; jj < 2; ++jj)
#pragma unroll
            for (int r = 0; r < 4; ++r)
              C[(long long)(rb0 + mh * 128 + ii * 16 + r) * 1024 +
                (((cb0 + nh * 128 + jj * 16)) & 1023)] =
                  (_Float16)acc[mh][ii][nh][jj][r];
  } else {
#pragma unroll
    for (int mh = 0; mh < 2; ++mh)
#pragma unroll
      for (int ii = 0; ii < 4; ++ii) {
        const int row = rb0 + mh * 128 + ii * 16;
        const int b = row >> 11, tok = row & 2047;
#pragma unroll
        for (int nh = 0; nh < 2; ++nh)
#pragma unroll
          for (int jj = 0; jj < 2; ++jj) {
            const int d = (cb0 - 2048) + nh * 128 + jj * 16;
            half4v v = { (_Float16)acc[mh][ii][nh][jj][0],
                         (_Float16)acc[mh][ii][nh][jj][1],
                         (_Float16)acc[mh][ii][nh][jj][2],
                         (_Float16)acc[mh][ii][nh][jj][3] };
            *(half4v*)&Vt[(long long)b * 2097152 + (long long)d * 2048 + tok] = v;
          }
      }
  }
}

// ---------------------------------------------------------------- S GEMM
// P_unnorm[128 q x 128 k] = exp(mask(Q K^T/32)) f16 + atomic row sums.
// VGPR-prefetch staging: ds_write(tile k) | barrier | load(tile k+1) | MFMA.
// Compact triangular grid bn <= bm (136 tiles/batch).
__global__ __launch_bounds__(256)
void gemm_s_exp(const _Float16* __restrict__ Q, const _Float16* __restrict__ Kh,
                _Float16* __restrict__ P, float* __restrict__ l) {
  int t = blockIdx.x;
  int bm = 0;
  for (;;) { const int c = bm + 1; if (t < c) break; t -= c; ++bm; }
  const int bn = t;
  const int bz = blockIdx.y;

  const _Float16* Ab = Q  + (long long)bz * 2097152 + (long long)bm * 128 * 1024;
  const _Float16* Bb = Kh + (long long)bz * 2097152 + (long long)bn * 128 * 1024;

  __shared__ _Float16 As[128][64];
  __shared__ _Float16 Bs[128][64];

  const int tid = threadIdx.x;
  const int wave = tid >> 6, lane = tid & 63;
  const int quad = lane >> 4, lr = lane & 15;
  const int wm = (wave >> 1) << 6, wn = (wave & 1) << 6;
  const int srow = lane >> 3;
  const int schunk = lane & 7;                 // LDS slot this lane fills
  const int goff = (schunk ^ srow) << 3;       // global chunk -> slot^(r&7)

  floatx4 acc[4][4] = {};
  const _Float16* ga = Ab + (long long)(wave * 8 + srow) * 1024 + goff;
  const _Float16* gb = Bb + (long long)(wave * 8 + srow) * 1024 + goff;

  half8 pa[4], pb[4];
#pragma unroll
  for (int c = 0; c < 4; ++c) {
    pa[c] = *(const half8*)(ga + c * 32 * 1024);
    pb[c] = *(const half8*)(gb + c * 32 * 1024);
  }

  for (int it = 0; it < 16; ++it) {
    __syncthreads();
#pragma unroll
    for (int c = 0; c < 4; ++c) {
      *(half8*)&As[wave * 8 + 32 * c + srow][schunk << 3] = pa[c];
      *(half8*)&Bs[wave * 8 + 32 * c + srow][schunk << 3] = pb[c];
    }
    __syncthreads();
    if (it + 1 < 16) {
      const int k1 = (it + 1) << 6;
#pragma unroll
      for (int c = 0; c < 4; ++c) {
        pa[c] = *(const half8*)(ga + c * 32 * 1024 + k1);
        pb[c] = *(const half8*)(gb + c * 32 * 1024 + k1);
      }
    }

#pragma unroll
    for (int kk = 0; kk < 2; ++kk) {
      half8 af[4], bf[4];
#pragma unroll
      for (int i = 0; i < 4; ++i) {
        const int ra = wm + (i << 4) + lr;
        const int rb = wn + (i << 4) + lr;
        af[i] = *(const half8*)&As[ra][(((kk << 2) + quad) ^ (ra & 7)) << 3];
        bf[i] = *(const half8*)&Bs[rb][(((kk << 2) + quad) ^ (rb & 7)) << 3];
      }
#pragma unroll
      for (int i = 0; i < 4; ++i)
#pragma unroll
        for (int j = 0; j < 4; ++j)
          acc[i][j] = __builtin_amdgcn_mfma_f32_16x16x32_f16(af[i], bf[j], acc[i][j], 0, 0, 0);
    }
  }

  // epilogue: p = exp(s/32) masked; f16 store; row-sum -> atomicAdd l[row]
  const int colb = bn * 128 + wn + lr;
  const int rowb = bm * 128 + wm + (quad << 2);
  _Float16* Pb = P + (long long)bz * 4194304;
  const float scl = 0.03125f;

  float rs[4][4];
#pragma unroll
  for (int i = 0; i < 4; ++i)
#pragma unroll
    for (int r = 0; r < 4; ++r) rs[i][r] = 0.f;

#pragma unroll
  for (int i = 0; i < 4; ++i)
#pragma unroll
    for (int j = 0; j < 4; ++j)
#pragma unroll
      for (int r = 0; r < 4; ++r) {
        const int q = rowb + (i << 4) + r;
        const int kcol = colb + (j << 4);
        const float pv = (kcol <= q) ? __expf(acc[i][j][r] * scl) : 0.f;
        Pb[(long long)q * 2048 + kcol] = (_Float16)pv;
        rs[i][r] += pv;
      }

#pragma unroll
  for (int i = 0; i < 4; ++i)
#pragma unroll
    for (int r = 0; r < 4; ++r) {
#pragma unroll
      for (int off = 1; off < 16; off <<= 1)
        rs[i][r] += __shfl_xor(rs[i][r], off);
    }
  if (lr == 0) {
    float* lb = l + bz * 2048;
#pragma unroll
    for (int i = 0; i < 4; ++i)
#pragma unroll
      for (int r = 0; r < 4; ++r)
        atomicAdd(&lb[rowb + (i << 4) + r], rs[i][r]);
  }
}

// ---------------------------------------------------------------- PV GEMM
// out[128 q x 128 d] = (P_unnorm V) / l[q]; Keff = 128*(bm+1); heavy-first.
// Same VGPR-prefetch staging; lda/ldb = 2048.
__global__ __launch_bounds__(256)
void gemm_pv(const _Float16* __restrict__ P, const _Float16* __restrict__ Vt,
             const float* __restrict__ l, float* __restrict__ out) {
  const int dn = blockIdx.x;           // 0..7
  const int bm = 15 - blockIdx.y;      // heavy (large Keff) first
  const int bz = blockIdx.z;
  const int niter = 2 * (bm + 1);      // Keff/64

  const _Float16* Ab = P  + (long long)bz * 4194304 + (long long)bm * 128 * 2048;
  const _Float16* Bb = Vt + (long long)bz * 2097152 + (long long)dn * 128 * 2048;

  __shared__ _Float16 As[128][64];
  __shared__ _Float16 Bs[128][64];

  const int tid = threadIdx.x;
  const int wave = tid >> 6, lane = tid & 63;
  const int quad = lane >> 4, lr = lane & 15;
  const int wm = (wave >> 1) << 6, wn = (wave & 1) << 6;
  const int srow = lane >> 3;
  const int schunk = lane & 7;
  const int goff = (schunk ^ srow) << 3;

  floatx4 acc[4][4] = {};
  const _Float16* ga = Ab + (long long)(wave * 8 + srow) * 2048 + goff;
  const _Float16* gb = Bb + (long long)(wave * 8 + srow) * 2048 + goff;

  half8 pa[4], pb[4];
#pragma unroll
  for (int c = 0; c < 4; ++c) {
    pa[c] = *(const half8*)(ga + (long long)c * 32 * 2048);
    pb[c] = *(const half8*)(gb + (long long)c * 32 * 2048);
  }

  for (int it = 0; it < niter; ++it) {
    __syncthreads();
#pragma unroll
    for (int c = 0; c < 4; ++c) {
      *(half8*)&As[wave * 8 + 32 * c + srow][schunk << 3] = pa[c];
      *(half8*)&Bs[wave * 8 + 32 * c + srow][schunk << 3] = pb[c];
    }
    __syncthreads();
    if (it + 1 < niter) {
      const int k1 = (it + 1) << 6;
#pragma unroll
      for (int c = 0; c < 4; ++c) {
        pa[c] = *(const half8*)(ga + (long long)c * 32 * 2048 + k1);
        pb[c] = *(const half8*)(gb + (long long)c * 32 * 2048 + k1);
      }
    }

#pragma unroll
    for (int kk = 0; kk < 2; ++kk) {
      half8 af[4], bf[4];
#pragma unroll
      for (int i = 0; i < 4; ++i) {
        const int ra = wm + (i << 4) + lr;
        const int rb = wn + (i << 4) + lr;
        af[i] = *(const half8*)&As[ra][(((kk << 2) + quad) ^ (ra & 7)) << 3];
        bf[i] = *(const half8*)&Bs[rb][(((kk << 2) + quad) ^ (rb & 7)) << 3];
      }
#pragma unroll
      for (int i = 0; i < 4; ++i)
#pragma unroll
        for (int j = 0; j < 4; ++j)
          acc[i][j] = __builtin_amdgcn_mfma_f32_16x16x32_f16(af[i], bf[j], acc[i][j], 0, 0, 0);
    }
  }

  const int colb = dn * 128 + wn + lr;
  const int rowb = bm * 128 + wm + (quad << 2);
  const float* lb = l + bz * 2048;
  float* Cb = out + (long long)bz * 2097152;

  float linv[4][4];
#pragma unroll
  for (int i = 0; i < 4; ++i)
#pragma unroll
    for (int r = 0; r < 4; ++r)
      linv[i][r] = 1.0f / lb[rowb + (i << 4) + r];

#pragma unroll
  for (int i = 0; i < 4; ++i)
#pragma unroll
    for (int j = 0; j < 4; ++j)
#pragma unroll
      for (int r = 0; r < 4; ++r)
        Cb[(long long)(rowb + (i << 4) + r) * 1024 + colb + (j << 4)] =
            acc[i][j][r] * linv[i][r];
}

// ---------------------------------------------------------------- launch

extern "C" void kernel_launch(void* const* d_in, const int* in_sizes, int n_in,
                              void* d_out, int out_size, void* d_ws, size_t ws_size,
                              hipStream_t stream) {
  const float* x  = (const float*)d_in[0];
  const float* Wq = (const float*)d_in[1];
  const float* Wk = (const float*)d_in[2];
  const float* Wv = (const float*)d_in[3];
  float* out = (float*)d_out;

  char* ws = (char*)d_ws;
  _Float16* xh = (_Float16*)(ws);               // 8192x1024 f16   (16 MiB)
  _Float16* Wt = (_Float16*)(ws + 16777216);    // 3072x1024 f16   ( 6 MiB)
  _Float16* Q  = (_Float16*)(ws + 23068672);    // 8192x1024 f16
  _Float16* Kh = (_Float16*)(ws + 39845888);    // 8192x1024 f16
  _Float16* Vt = (_Float16*)(ws + 56623104);    // 4x1024x2048 f16
  _Float16* P  = (_Float16*)(ws + 73400320);    // 4x2048x2048 f16 unnormalized
  float*    l  = (float*)   (ws + 106954752);   // 4x2048 fp32 row sums

  conv_f32_f16<<<8200, 256, 0, stream>>>(x, xh, l);
  transpose_w<<<dim3(32, 32, 3), dim3(32, 8), 0, stream>>>(Wq, Wk, Wv, Wt);

  // fused QKV: [8192,1024] x [3072,1024]^T, 256^2 8-phase
  gemm_qkv<<<dim3(384), 512, 0, stream>>>(xh, Wt, Q, Kh, Vt);

  // P_unnorm = exp(mask(Q K^T / 32)) + row sums; compact triangular grid
  gemm_s_exp<<<dim3(136, 4), 256, 0, stream>>>(Q, Kh, P, l);

  // out = (P V) / l; causal K-limit at 128 gran, heavy-first
  gemm_pv<<<dim3(8, 16, 4), 256, 0, stream>>>(P, Vt, l, out);
}

// Round 2
// 239.175 us; speedup vs baseline: 1.0763x; 1.0763x over previous
//
#include <hip/hip_runtime.h>

// CausalSelfAttention B=4, N=2048, D=1024, scale 1/32.
// f16 convert(+zero l) -> fused QKV GEMM -> S=QK^T 128x128 (fused mask+exp +
// atomic row sums) -> PV 128x128 (causal K-limit, heavy-first) / rowsum.
//
// R13: QKV 8-phase repaired after R12 regression (91.7us, MfmaUtil 22%).
// R12 failure diagnosed: (a) 12 ds_read_b128/phase (2x redundant re-reads) ->
// 393KB/K-tile LDS-read at ~85B/cyc = 1.9x MFMA time -> LDS-read-bound ~54%;
// (b) 384 blocks = 1.5 rounds -> x0.75 tail. Fix: (a) minimal-read phases
// (mh,kk) quadrants reading only the changed operand: 7/7/4/4 reads/phase =
// 22/K-tile (the sharing minimum; both B k-halves held in regs); (b) BM=256
// BN=192 -> 512 blocks = exactly 2 rounds. Counted vmcnt(2) at ph4/ph8 only;
// region-liveness: A staged as interleaved mh-half units (die after 2 phases),
// B whole (dies at tile end). S/PV unchanged (R11 VGPR-prefetch 2-phase).

typedef __attribute__((ext_vector_type(8))) _Float16 half8;
typedef __attribute__((ext_vector_type(4))) _Float16 half4v;
typedef __attribute__((ext_vector_type(4))) float floatx4;

#define AS1 __attribute__((address_space(1)))
#define AS3 __attribute__((address_space(3)))

__device__ __forceinline__ void load16_lds(void* lds, const void* g) {
  __builtin_amdgcn_global_load_lds((AS1 void*)g, (AS3 void*)lds, 16, 0, 0);
}

// ---------------------------------------------------------------- conv + zero

__global__ __launch_bounds__(256)
void conv_f32_f16(const float* __restrict__ in, _Float16* __restrict__ out,
                  float* __restrict__ l) {
  if (blockIdx.x < 8192) {
    const int i = (blockIdx.x * 256 + threadIdx.x) << 2;
    float4 v = *(const float4*)(in + i);
    half4v o = { (_Float16)v.x, (_Float16)v.y, (_Float16)v.z, (_Float16)v.w };
    *(half4v*)(out + i) = o;
  } else {
    const int i = ((blockIdx.x - 8192) * 256 + threadIdx.x) << 2;
    *(float4*)(l + i) = float4{0.f, 0.f, 0.f, 0.f};
  }
}

// W [1024(k),1024(n)] fp32 -> Wt [n][k] f16 for 3 weights -> [3072][1024]
__global__ __launch_bounds__(256)
void transpose_w(const float* __restrict__ W0, const float* __restrict__ W1,
                 const float* __restrict__ W2, _Float16* __restrict__ Wt) {
  const float* W = blockIdx.z == 0 ? W0 : (blockIdx.z == 1 ? W1 : W2);
  _Float16* out = Wt + (long long)blockIdx.z * 1048576;
  __shared__ _Float16 t[32][33];
  const int tx = threadIdx.x, ty = threadIdx.y;
  const int n0 = blockIdx.x << 5, k0 = blockIdx.y << 5;
#pragma unroll
  for (int i = 0; i < 4; ++i)
    t[ty + i * 8][tx] = (_Float16)W[(long long)(k0 + ty + i * 8) * 1024 + n0 + tx];
  __syncthreads();
#pragma unroll
  for (int i = 0; i < 4; ++i)
    out[(long long)(n0 + ty + i * 8) * 1024 + k0 + tx] = t[tx][ty + i * 8];
}

// ---------------------------------------------------------------- QKV GEMM
// 256x192 tile, BK=64, 512 threads (8 waves 2Mx4N, per-wave 128x48).
// 8-phase: per K-tile quadrants (mh,kk) = (0,0),(0,1),(1,1),(1,0).
__global__ __launch_bounds__(512)
void gemm_qkv(const _Float16* __restrict__ A, const _Float16* __restrict__ B,
              _Float16* __restrict__ Q, _Float16* __restrict__ Kh,
              _Float16* __restrict__ Vt) {
  // bijective XCD swizzle: 512 blocks, 64 per XCD
  const int wg = ((blockIdx.x & 7) << 6) + (blockIdx.x >> 3);
  const int bm = wg >> 4, bn = wg & 15;   // 32 x 16

  const _Float16* Ab = A + (long long)bm * 256 * 1024;
  const _Float16* Bb = B + (long long)bn * 192 * 1024;

  __shared__ _Float16 As[2][256][64];   // 64 KiB
  __shared__ _Float16 Bs[2][192][64];   // 48 KiB

  const int tid = threadIdx.x;
  const int wave = tid >> 6, lane = tid & 63;
  const int quad = lane >> 4, lr = lane & 15;
  const int rowb = (wave >> 2) << 7;    // 0 / 128
  const int colb = (wave & 3) * 48;     // 0,48,96,144
  const int srow = lane >> 3;
  const int goff = ((lane & 7) ^ srow) << 3;  // pre-swizzled global chunk

  const _Float16* gA = Ab + (long long)srow * 1024 + goff;
  const _Float16* gB = Bb + (long long)srow * 1024 + goff;

  // A stage units: unit (mh): rows {0-63 u 128-191} + mh*64, 2 calls/thread.
  // B unit: all 192 rows, 3 calls/thread. All row bases wave-uniform.
  int arow[2][2], brow[3];
#pragma unroll
  for (int c = 0; c < 2; ++c) {
    const int li = wave * 16 + c * 8;
    const int r0 = (li < 64) ? li : li + 64;
    arow[0][c] = r0;
    arow[1][c] = r0 + 64;
  }
#pragma unroll
  for (int c = 0; c < 3; ++c) brow[c] = wave * 24 + c * 8;

  floatx4 acc[2][4][3] = {};
  half8 af[4], bf[2][3];

#define STAGE_A(buf, mh, kt)                                                  \
  _Pragma("unroll") for (int c = 0; c < 2; ++c)                               \
    load16_lds(&As[buf][arow[mh][c]][0],                                      \
               gA + (long long)arow[mh][c] * 1024 + (long long)(kt) * 64)

#define STAGE_B(buf, kt)                                                      \
  _Pragma("unroll") for (int c = 0; c < 3; ++c)                               \
    load16_lds(&Bs[buf][brow[c]][0],                                          \
               gB + (long long)brow[c] * 1024 + (long long)(kt) * 64)

#define DSRA(buf, mh, kk)                                                     \
  _Pragma("unroll") for (int ii = 0; ii < 4; ++ii) {                          \
    const int ra = rowb + (mh) * 64 + (ii << 4) + lr;                         \
    af[ii] = *(const half8*)&As[buf][ra][((((kk) << 2) + quad) ^ (ra & 7)) << 3]; \
  }

#define DSRB(buf, kk)                                                         \
  _Pragma("unroll") for (int jj = 0; jj < 3; ++jj) {                          \
    const int rb = colb + (jj << 4) + lr;                                     \
    bf[kk][jj] = *(const half8*)&Bs[buf][rb][((((kk) << 2) + quad) ^ (rb & 7)) << 3]; \
  }

#define MFMA12(mh, kk)                                                        \
  __builtin_amdgcn_s_setprio(1);                                              \
  _Pragma("unroll") for (int ii = 0; ii < 4; ++ii)                            \
  _Pragma("unroll") for (int jj = 0; jj < 3; ++jj)                            \
    acc[mh][ii][jj] = __builtin_amdgcn_mfma_f32_16x16x32_f16(                 \
        af[ii], bf[kk][jj], acc[mh][ii][jj], 0, 0, 0);                        \
  __builtin_amdgcn_s_setprio(0)

#define BAR() __builtin_amdgcn_s_barrier()
#define LGKM0()                                                               \
  do { asm volatile("s_waitcnt lgkmcnt(0)");                                  \
       __builtin_amdgcn_sched_barrier(0); } while (0)
#define VM2()                                                                 \
  do { asm volatile("s_waitcnt vmcnt(2)");                                    \
       __builtin_amdgcn_sched_barrier(0); } while (0)
#define VM0()                                                                 \
  do { asm volatile("s_waitcnt vmcnt(0)");                                    \
       __builtin_amdgcn_sched_barrier(0); } while (0)

  // prologue: tile0 full -> buf0 (7 loads), tile1 A0-unit -> buf1 (2 loads)
  STAGE_A(0, 0, 0); STAGE_A(0, 1, 0); STAGE_B(0, 0);
  STAGE_A(1, 0, 1);
  VM2();   // tile0's 7 landed; tile1-A0's 2 may stay in flight
  BAR();

  // steady: consume tile 2i (buf0, ph1-4) and 2i+1 (buf1, ph5-8).
  // Stage rotation (each unit restaged exactly one phase after it dies):
  //   ph1: A1(buf1,t1)  ph2: B(buf1,t1)  ph3: A0(buf0,t2)  ph4: - vmcnt(2)
  //   ph5: A1(buf0,t2)  ph6: B(buf0,t2)  ph7: A0(buf1,t3)  ph8: - vmcnt(2)
  for (int i = 0; i < 7; ++i) {
    const int t1 = 2 * i + 1, t2 = 2 * i + 2, t3 = 2 * i + 3;
    DSRA(0,0,0); DSRB(0,0); STAGE_A(1,1,t1); BAR(); LGKM0(); MFMA12(0,0); BAR();
    DSRA(0,0,1); DSRB(0,1); STAGE_B(1,t1);   BAR(); LGKM0(); MFMA12(0,1); BAR();
    DSRA(0,1,1);            STAGE_A(0,0,t2); BAR(); LGKM0(); MFMA12(1,1); BAR();
    DSRA(0,1,0);                             BAR(); LGKM0(); MFMA12(1,0); VM2(); BAR();
    DSRA(1,0,0); DSRB(1,0); STAGE_A(0,1,t2); BAR(); LGKM0(); MFMA12(0,0); BAR();
    DSRA(1,0,1); DSRB(1,1); STAGE_B(0,t2);   BAR(); LGKM0(); MFMA12(0,1); BAR();
    DSRA(1,1,1);            STAGE_A(1,0,t3); BAR(); LGKM0(); MFMA12(1,1); BAR();
    DSRA(1,1,0);                             BAR(); LGKM0(); MFMA12(1,0); VM2(); BAR();
  }

  // peeled last iter: tiles 14 (buf0) / 15 (buf1); finish t15, then drain
  DSRA(0,0,0); DSRB(0,0); STAGE_A(1,1,15); BAR(); LGKM0(); MFMA12(0,0); BAR();
  DSRA(0,0,1); DSRB(0,1); STAGE_B(1,15);   BAR(); LGKM0(); MFMA12(0,1); BAR();
  DSRA(0,1,1);                             BAR(); LGKM0(); MFMA12(1,1); BAR();
  DSRA(0,1,0);                             BAR(); LGKM0(); MFMA12(1,0); VM0(); BAR();
  DSRA(1,0,0); DSRB(1,0);                  BAR(); LGKM0(); MFMA12(0,0); BAR();
  DSRA(1,0,1); DSRB(1,1);                  BAR(); LGKM0(); MFMA12(0,1); BAR();
  DSRA(1,1,1);                             BAR(); LGKM0(); MFMA12(1,1); BAR();
  DSRA(1,1,0);                             BAR(); LGKM0(); MFMA12(1,0);

#undef STAGE_A
#undef STAGE_B
#undef DSRA
#undef DSRB
#undef MFMA12
#undef BAR
#undef LGKM0
#undef VM2
#undef VM0

  // epilogue: row = bm*256 + rowb + mh*64 + ii*16 + quad*4 + r
  //           col = bn*192 + colb + jj*16 + lr; route per 16-col fragment
  const int row0 = bm * 256 + rowb + (quad << 2);
  const int col0 = bn * 192 + colb + lr;

#pragma unroll
  for (int mh = 0; mh < 2; ++mh)
#pragma unroll
    for (int ii = 0; ii < 4; ++ii) {
      const int row = row0 + mh * 64 + ii * 16;
#pragma unroll
      for (int jj = 0; jj < 3; ++jj) {
        const int cseg = (bn * 192 + colb + jj * 16) >> 10;  // wave-uniform
        const int col = col0 + jj * 16;
        if (cseg < 2) {
          _Float16* C = (cseg == 0) ? Q : Kh;
          const int cc = col & 1023;
#pragma unroll
          for (int r = 0; r < 4; ++r)
            C[(long long)(row + r) * 1024 + cc] = (_Float16)acc[mh][ii][jj][r];
        } else {
          const int b = row >> 11, tok = row & 2047;
          const int d = col & 1023;
          half4v v = { (_Float16)acc[mh][ii][jj][0], (_Float16)acc[mh][ii][jj][1],
                       (_Float16)acc[mh][ii][jj][2], (_Float16)acc[mh][ii][jj][3] };
          *(half4v*)&Vt[(long long)b * 2097152 + (long long)d * 2048 + tok] = v;
        }
      }
    }
}

// ---------------------------------------------------------------- S GEMM
// P_unnorm[128 q x 128 k] = exp(mask(Q K^T/32)) f16 + atomic row sums.
// VGPR-prefetch staging: ds_write(tile k) | barrier | load(tile k+1) | MFMA.
// Compact triangular grid bn <= bm (136 tiles/batch).
__global__ __launch_bounds__(256)
void gemm_s_exp(const _Float16* __restrict__ Q, const _Float16* __restrict__ Kh,
                _Float16* __restrict__ P, float* __restrict__ l) {
  int t = blockIdx.x;
  int bm = 0;
  for (;;) { const int c = bm + 1; if (t < c) break; t -= c; ++bm; }
  const int bn = t;
  const int bz = blockIdx.y;

  const _Float16* Ab = Q  + (long long)bz * 2097152 + (long long)bm * 128 * 1024;
  const _Float16* Bb = Kh + (long long)bz * 2097152 + (long long)bn * 128 * 1024;

  __shared__ _Float16 As[128][64];
  __shared__ _Float16 Bs[128][64];

  const int tid = threadIdx.x;
  const int wave = tid >> 6, lane = tid & 63;
  const int quad = lane >> 4, lr = lane & 15;
  const int wm = (wave >> 1) << 6, wn = (wave & 1) << 6;
  const int srow = lane >> 3;
  const int schunk = lane & 7;                 // LDS slot this lane fills
  const int goff = (schunk ^ srow) << 3;       // global chunk -> slot^(r&7)

  floatx4 acc[4][4] = {};
  const _Float16* ga = Ab + (long long)(wave * 8 + srow) * 1024 + goff;
  const _Float16* gb = Bb + (long long)(wave * 8 + srow) * 1024 + goff;

  half8 pa[4], pb[4];
#pragma unroll
  for (int c = 0; c < 4; ++c) {
    pa[c] = *(const half8*)(ga + c * 32 * 1024);
    pb[c] = *(const half8*)(gb + c * 32 * 1024);
  }

  for (int it = 0; it < 16; ++it) {
    __syncthreads();
#pragma unroll
    for (int c = 0; c < 4; ++c) {
      *(half8*)&As[wave * 8 + 32 * c + srow][schunk << 3] = pa[c];
      *(half8*)&Bs[wave * 8 + 32 * c + srow][schunk << 3] = pb[c];
    }
    __syncthreads();
    if (it + 1 < 16) {
      const int k1 = (it + 1) << 6;
#pragma unroll
      for (int c = 0; c < 4; ++c) {
        pa[c] = *(const half8*)(ga + c * 32 * 1024 + k1);
        pb[c] = *(const half8*)(gb + c * 32 * 1024 + k1);
      }
    }

#pragma unroll
    for (int kk = 0; kk < 2; ++kk) {
      half8 af[4], bf[4];
#pragma unroll
      for (int i = 0; i < 4; ++i) {
        const int ra = wm + (i << 4) + lr;
        const int rb = wn + (i << 4) + lr;
        af[i] = *(const half8*)&As[ra][(((kk << 2) + quad) ^ (ra & 7)) << 3];
        bf[i] = *(const half8*)&Bs[rb][(((kk << 2) + quad) ^ (rb & 7)) << 3];
      }
#pragma unroll
      for (int i = 0; i < 4; ++i)
#pragma unroll
        for (int j = 0; j < 4; ++j)
          acc[i][j] = __builtin_amdgcn_mfma_f32_16x16x32_f16(af[i], bf[j], acc[i][j], 0, 0, 0);
    }
  }

  // epilogue: p = exp(s/32) masked; f16 store; row-sum -> atomicAdd l[row]
  const int colb = bn * 128 + wn + lr;
  const int rowb = bm * 128 + wm + (quad << 2);
  _Float16* Pb = P + (long long)bz * 4194304;
  const float scl = 0.03125f;

  float rs[4][4];
#pragma unroll
  for (int i = 0; i < 4; ++i)
#pragma unroll
    for (int r = 0; r < 4; ++r) rs[i][r] = 0.f;

#pragma unroll
  for (int i = 0; i < 4; ++i)
#pragma unroll
    for (int j = 0; j < 4; ++j)
#pragma unroll
      for (int r = 0; r < 4; ++r) {
        const int q = rowb + (i << 4) + r;
        const int kcol = colb + (j << 4);
        const float pv = (kcol <= q) ? __expf(acc[i][j][r] * scl) : 0.f;
        Pb[(long long)q * 2048 + kcol] = (_Float16)pv;
        rs[i][r] += pv;
      }

#pragma unroll
  for (int i = 0; i < 4; ++i)
#pragma unroll
    for (int r = 0; r < 4; ++r) {
#pragma unroll
      for (int off = 1; off < 16; off <<= 1)
        rs[i][r] += __shfl_xor(rs[i][r], off);
    }
  if (lr == 0) {
    float* lb = l + bz * 2048;
#pragma unroll
    for (int i = 0; i < 4; ++i)
#pragma unroll
      for (int r = 0; r < 4; ++r)
        atomicAdd(&lb[rowb + (i << 4) + r], rs[i][r]);
  }
}

// ---------------------------------------------------------------- PV GEMM
// out[128 q x 128 d] = (P_unnorm V) / l[q]; Keff = 128*(bm+1); heavy-first.
// Same VGPR-prefetch staging; lda/ldb = 2048.
__global__ __launch_bounds__(256)
void gemm_pv(const _Float16* __restrict__ P, const _Float16* __restrict__ Vt,
             const float* __restrict__ l, float* __restrict__ out) {
  const int dn = blockIdx.x;           // 0..7
  const int bm = 15 - blockIdx.y;      // heavy (large Keff) first
  const int bz = blockIdx.z;
  const int niter = 2 * (bm + 1);      // Keff/64

  const _Float16* Ab = P  + (long long)bz * 4194304 + (long long)bm * 128 * 2048;
  const _Float16* Bb = Vt + (long long)bz * 2097152 + (long long)dn * 128 * 2048;

  __shared__ _Float16 As[128][64];
  __shared__ _Float16 Bs[128][64];

  const int tid = threadIdx.x;
  const int wave = tid >> 6, lane = tid & 63;
  const int quad = lane >> 4, lr = lane & 15;
  const int wm = (wave >> 1) << 6, wn = (wave & 1) << 6;
  const int srow = lane >> 3;
  const int schunk = lane & 7;
  const int goff = (schunk ^ srow) << 3;

  floatx4 acc[4][4] = {};
  const _Float16* ga = Ab + (long long)(wave * 8 + srow) * 2048 + goff;
  const _Float16* gb = Bb + (long long)(wave * 8 + srow) * 2048 + goff;

  half8 pa[4], pb[4];
#pragma unroll
  for (int c = 0; c < 4; ++c) {
    pa[c] = *(const half8*)(ga + (long long)c * 32 * 2048);
    pb[c] = *(const half8*)(gb + (long long)c * 32 * 2048);
  }

  for (int it = 0; it < niter; ++it) {
    __syncthreads();
#pragma unroll
    for (int c = 0; c < 4; ++c) {
      *(half8*)&As[wave * 8 + 32 * c + srow][schunk << 3] = pa[c];
      *(half8*)&Bs[wave * 8 + 32 * c + srow][schunk << 3] = pb[c];
    }
    __syncthreads();
    if (it + 1 < niter) {
      const int k1 = (it + 1) << 6;
#pragma unroll
      for (int c = 0; c < 4; ++c) {
        pa[c] = *(const half8*)(ga + (long long)c * 32 * 2048 + k1);
        pb[c] = *(const half8*)(gb + (long long)c * 32 * 2048 + k1);
      }
    }

#pragma unroll
    for (int kk = 0; kk < 2; ++kk) {
      half8 af[4], bf[4];
#pragma unroll
      for (int i = 0; i < 4; ++i) {
        const int ra = wm + (i << 4) + lr;
        const int rb = wn + (i << 4) + lr;
        af[i] = *(const half8*)&As[ra][(((kk << 2) + quad) ^ (ra & 7)) << 3];
        bf[i] = *(const half8*)&Bs[rb][(((kk << 2) + quad) ^ (rb & 7)) << 3];
      }
#pragma unroll
      for (int i = 0; i < 4; ++i)
#pragma unroll
        for (int j = 0; j < 4; ++j)
          acc[i][j] = __builtin_amdgcn_mfma_f32_16x16x32_f16(af[i], bf[j], acc[i][j], 0, 0, 0);
    }
  }

  const int colb = dn * 128 + wn + lr;
  const int rowb = bm * 128 + wm + (quad << 2);
  const float* lb = l + bz * 2048;
  float* Cb = out + (long long)bz * 2097152;

  float linv[4][4];
#pragma unroll
  for (int i = 0; i < 4; ++i)
#pragma unroll
    for (int r = 0; r < 4; ++r)
      linv[i][r] = 1.0f / lb[rowb + (i << 4) + r];

#pragma unroll
  for (int i = 0; i < 4; ++i)
#pragma unroll
    for (int j = 0; j < 4; ++j)
#pragma unroll
      for (int r = 0; r < 4; ++r)
        Cb[(long long)(rowb + (i << 4) + r) * 1024 + colb + (j << 4)] =
            acc[i][j][r] * linv[i][r];
}

// ---------------------------------------------------------------- launch

extern "C" void kernel_launch(void* const* d_in, const int* in_sizes, int n_in,
                              void* d_out, int out_size, void* d_ws, size_t ws_size,
                              hipStream_t stream) {
  const float* x  = (const float*)d_in[0];
  const float* Wq = (const float*)d_in[1];
  const float* Wk = (const float*)d_in[2];
  const float* Wv = (const float*)d_in[3];
  float* out = (float*)d_out;

  char* ws = (char*)d_ws;
  _Float16* xh = (_Float16*)(ws);               // 8192x1024 f16   (16 MiB)
  _Float16* Wt = (_Float16*)(ws + 16777216);    // 3072x1024 f16   ( 6 MiB)
  _Float16* Q  = (_Float16*)(ws + 23068672);    // 8192x1024 f16
  _Float16* Kh = (_Float16*)(ws + 39845888);    // 8192x1024 f16
  _Float16* Vt = (_Float16*)(ws + 56623104);    // 4x1024x2048 f16
  _Float16* P  = (_Float16*)(ws + 73400320);    // 4x2048x2048 f16 unnormalized
  float*    l  = (float*)   (ws + 106954752);   // 4x2048 fp32 row sums

  conv_f32_f16<<<8200, 256, 0, stream>>>(x, xh, l);
  transpose_w<<<dim3(32, 32, 3), dim3(32, 8), 0, stream>>>(Wq, Wk, Wv, Wt);

  // fused QKV: [8192,1024] x [3072,1024]^T, 256x192 8-phase, 512 blocks
  gemm_qkv<<<dim3(512), 512, 0, stream>>>(xh, Wt, Q, Kh, Vt);

  // P_unnorm = exp(mask(Q K^T / 32)) + row sums; compact triangular grid
  gemm_s_exp<<<dim3(136, 4), 256, 0, stream>>>(Q, Kh, P, l);

  // out = (P V) / l; causal K-limit at 128 gran, heavy-first
  gemm_pv<<<dim3(8, 16, 4), 256, 0, stream>>>(P, Vt, l, out);
}